// Round 1
// baseline (1905.531 us; speedup 1.0000x reference)
//
#include <hip/hip_runtime.h>
#include <math.h>

#define NROWS 16
#define DIM 1024
#define RANK 256
#define NT 256
#define NWAVE 4
#define TOTAL_ROWS 4096
#define OUT_HALF (TOTAL_ROWS * DIM)

static constexpr double d_XI  = 0.1786178958448091;
static constexpr double d_LAM = -0.2123418310626054;
static constexpr double d_CHI = -0.0662645826698185;
static constexpr double d_DT  = 0.01;

// LDS layout (floats):
//   vs   [NROWS][DIM]          16384
//   h2s  [NROWS][RANK]          4096
//   hpart[NWAVE][NROWS][RANK]  16384
//   wsums[NROWS][NWAVE]           64
//   sings[NROWS]                  16
#define SMEM_FLOATS (NROWS*DIM + NROWS*RANK + NWAVE*NROWS*RANK + NROWS*NWAVE + NROWS)
#define SMEM_BYTES  (SMEM_FLOATS * 4)

__global__ __launch_bounds__(NT, 1)
void omelyan_kernel(const float* __restrict__ x_in,
                    const float* __restrict__ v_in,
                    const float* __restrict__ force,
                    const float* __restrict__ Umat,
                    const float* __restrict__ Wmat,
                    const float* __restrict__ Vw,
                    const int* __restrict__ steps_p,
                    float* __restrict__ out)
{
    extern __shared__ float smem[];
    float* vs    = smem;                          // [NROWS][DIM]
    float* h2s   = vs + NROWS * DIM;              // [NROWS][RANK]
    float* hpart = h2s + NROWS * RANK;            // [NWAVE][NROWS][RANK]
    float* wsums = hpart + NWAVE * NROWS * RANK;  // [NROWS][NWAVE]
    float* sings = wsums + NROWS * NWAVE;         // [NROWS]

    const int t    = threadIdx.x;
    const int lane = t & 63;
    const int wave = t >> 6;
    const int row0 = blockIdx.x * NROWS;
    const int nsteps = steps_p[0];

    const float dt = (float)d_DT;
    const float cs[4]   = {(float)d_XI, (float)d_CHI,
                           (float)(1.0 - 2.0*(d_CHI + d_XI)), (float)d_CHI};
    const float dsub[4] = {(float)((1.0 - 2.0*d_LAM)*0.5), (float)d_LAM,
                           (float)d_LAM, (float)((1.0 - 2.0*d_LAM)*0.5)};
    const float c5dt = (float)d_XI * dt;

    // per-thread elementwise state: element (m, d = t + 256*jj)
    float xr[NROWS][4], vr[NROWS][4];
    float vwv[4];
    #pragma unroll
    for (int jj = 0; jj < 4; ++jj) vwv[jj] = Vw[t + 256*jj];

    #pragma unroll
    for (int m = 0; m < NROWS; ++m) {
        const int base = (row0 + m) * DIM + t;
        #pragma unroll
        for (int jj = 0; jj < 4; ++jj) {
            xr[m][jj] = x_in[base + 256*jj];
            vr[m][jj] = v_in[base + 256*jj];
            vs[m*DIM + t + 256*jj] = vr[m][jj];
        }
    }
    __syncthreads();

    #pragma unroll 1
    for (int step = 0; step < nsteps; ++step) {
        #pragma unroll 1
        for (int sub = 0; sub < 4; ++sub) {
            const float cdt = cs[sub] * dt;
            const float ddt = dsub[sub] * dt;

            // ---- x drift + r2 partials (registers only) ----
            float pr2[NROWS];
            #pragma unroll
            for (int m = 0; m < NROWS; ++m) {
                float s = 0.0f;
                #pragma unroll
                for (int jj = 0; jj < 4; ++jj) {
                    xr[m][jj] = fmaf(cdt, vr[m][jj], xr[m][jj]);
                    s = fmaf(xr[m][jj], xr[m][jj], s);
                }
                pr2[m] = s;
            }
            // wave-level reduce, then deterministic cross-wave sum
            #pragma unroll
            for (int m = 0; m < NROWS; ++m) {
                float s = pr2[m];
                #pragma unroll
                for (int off = 32; off >= 1; off >>= 1)
                    s += __shfl_xor(s, off, 64);
                if (lane == 0) wsums[m*NWAVE + wave] = s;
            }
            __syncthreads();                       // b1
            if (t < NROWS) {
                float r2 = wsums[t*NWAVE] + wsums[t*NWAVE+1]
                         + wsums[t*NWAVE+2] + wsums[t*NWAVE+3];
                sings[t] = 1.0f + expf(-r2);       // SING_STRENGTH=1, THRESH=1
            }

            // ---- phase H: h = v @ U, K(=d) split across waves ----
            float hacc[NROWS][4];
            #pragma unroll
            for (int m = 0; m < NROWS; ++m)
                #pragma unroll
                for (int j = 0; j < 4; ++j) hacc[m][j] = 0.0f;

            const int d0 = wave * 256;
            #pragma unroll 1
            for (int dc = 0; dc < 256; dc += 4) {
                float uv[4][4];
                #pragma unroll
                for (int dd = 0; dd < 4; ++dd)
                    #pragma unroll
                    for (int j = 0; j < 4; ++j)
                        uv[dd][j] = Umat[(d0 + dc + dd)*RANK + lane + 64*j];
                #pragma unroll
                for (int m = 0; m < NROWS; ++m) {
                    const float4 vv = *(const float4*)&vs[m*DIM + d0 + dc];
                    const float vvf[4] = {vv.x, vv.y, vv.z, vv.w};
                    #pragma unroll
                    for (int dd = 0; dd < 4; ++dd)
                        #pragma unroll
                        for (int j = 0; j < 4; ++j)
                            hacc[m][j] = fmaf(vvf[dd], uv[dd][j], hacc[m][j]);
                }
            }
            #pragma unroll
            for (int m = 0; m < NROWS; ++m)
                #pragma unroll
                for (int j = 0; j < 4; ++j)
                    hpart[(wave*NROWS + m)*RANK + lane + 64*j] = hacc[m][j];
            __syncthreads();                       // b2

            // reduce partials -> h2 = h*h
            #pragma unroll
            for (int m = 0; m < NROWS; ++m) {
                float h = hpart[(0*NROWS + m)*RANK + t]
                        + hpart[(1*NROWS + m)*RANK + t]
                        + hpart[(2*NROWS + m)*RANK + t]
                        + hpart[(3*NROWS + m)*RANK + t];
                h2s[m*RANK + t] = h * h;
            }
            __syncthreads();                       // b3

            // ---- phase G: gamma = h2 @ W, then v kick ----
            float gacc[NROWS][4];
            #pragma unroll
            for (int m = 0; m < NROWS; ++m)
                #pragma unroll
                for (int j = 0; j < 4; ++j) gacc[m][j] = 0.0f;

            #pragma unroll 1
            for (int rc = 0; rc < RANK; rc += 4) {
                float wv[4][4];
                #pragma unroll
                for (int rr = 0; rr < 4; ++rr)
                    #pragma unroll
                    for (int j = 0; j < 4; ++j)
                        wv[rr][j] = Wmat[(rc + rr)*DIM + t + 256*j];
                #pragma unroll
                for (int m = 0; m < NROWS; ++m) {
                    const float4 hv = *(const float4*)&h2s[m*RANK + rc];
                    const float hvf[4] = {hv.x, hv.y, hv.z, hv.w};
                    #pragma unroll
                    for (int rr = 0; rr < 4; ++rr)
                        #pragma unroll
                        for (int j = 0; j < 4; ++j)
                            gacc[m][j] = fmaf(hvf[rr], wv[rr][j], gacc[m][j]);
                }
            }

            // v kick: v += ddt * (force - gamma*gate*sing); refresh vs
            #pragma unroll
            for (int m = 0; m < NROWS; ++m) {
                const float sing = sings[m];
                const int fbase = (row0 + m) * DIM + t;
                #pragma unroll
                for (int jj = 0; jj < 4; ++jj) {
                    const float gate = fmaf(0.1f, tanhf(xr[m][jj] * vwv[jj]), 1.0f);
                    const float acc  = force[fbase + 256*jj]
                                     - gacc[m][jj] * gate * sing;
                    vr[m][jj] = fmaf(ddt, acc, vr[m][jj]);
                    vs[m*DIM + t + 256*jj] = vr[m][jj];
                }
            }
            __syncthreads();                       // b4
        } // sub

        // final drift of the step: x += C5*dt*v
        #pragma unroll
        for (int m = 0; m < NROWS; ++m)
            #pragma unroll
            for (int jj = 0; jj < 4; ++jj)
                xr[m][jj] = fmaf(c5dt, vr[m][jj], xr[m][jj]);
    } // step

    // ---- store (x, v) concatenated ----
    #pragma unroll
    for (int m = 0; m < NROWS; ++m) {
        const int base = (row0 + m) * DIM + t;
        #pragma unroll
        for (int jj = 0; jj < 4; ++jj) {
            out[base + 256*jj]            = xr[m][jj];
            out[OUT_HALF + base + 256*jj] = vr[m][jj];
        }
    }
}

extern "C" void kernel_launch(void* const* d_in, const int* in_sizes, int n_in,
                              void* d_out, int out_size, void* d_ws, size_t ws_size,
                              hipStream_t stream) {
    const float* x_in  = (const float*)d_in[0];
    const float* v_in  = (const float*)d_in[1];
    const float* force = (const float*)d_in[2];
    const float* Umat  = (const float*)d_in[3];
    const float* Wmat  = (const float*)d_in[4];
    const float* Vw    = (const float*)d_in[5];
    const int*   steps = (const int*)d_in[6];
    float* out = (float*)d_out;

    // allow >64KB dynamic LDS (147776 B); idempotent, host-side, capture-safe
    (void)hipFuncSetAttribute((const void*)omelyan_kernel,
                              hipFuncAttributeMaxDynamicSharedMemorySize,
                              SMEM_BYTES);

    omelyan_kernel<<<dim3(TOTAL_ROWS / NROWS), dim3(NT), SMEM_BYTES, stream>>>(
        x_in, v_in, force, Umat, Wmat, Vw, steps, out);
}

// Round 2
// 869.627 us; speedup vs baseline: 2.1912x; 2.1912x over previous
//
#include <hip/hip_runtime.h>
#include <math.h>

typedef short  bf16x8 __attribute__((ext_vector_type(8)));
typedef float  f32x4  __attribute__((ext_vector_type(4)));
typedef unsigned short us4 __attribute__((ext_vector_type(4)));

#define DIM   1024
#define RANK  256
#define NROWS 16
#define NTHREADS 256
#define TOTAL_ROWS 4096
#define OUT_HALF (TOTAL_ROWS*DIM)

// LDS byte layout
#define VS_OFF   0            // ushort[16][1024], XOR-swizzled rows
#define H2_OFF   32768        // ushort[16][256],  XOR-swizzled rows
#define GS_OFF   40960        // float [16][1028] (pitch-padded)
#define GS_PITCH 1028
#define WS_OFF   106752       // float [16][4]
#define SG_OFF   107008       // float [16]
#define SMEM_BYTES 107072

static constexpr double XI  = 0.1786178958448091;
static constexpr double LAM = -0.2123418310626054;
static constexpr double CHI = -0.0662645826698185;

__device__ __forceinline__ unsigned short f2bf(float f) {
    unsigned u = __builtin_bit_cast(unsigned, f);
    u += 0x7FFFu + ((u >> 16) & 1u);        // round-to-nearest-even
    return (unsigned short)(u >> 16);
}

// swizzled LDS addressing: byte ^= (row&7)<<4 spreads the 16 A-rows over
// 8 distinct 16B slots -> 2-way conflict (free) on ds_read_b128
__device__ __forceinline__ int vs_addr(int m, int kb) {
    return VS_OFF + ((m * 2048 + kb) ^ ((m & 7) << 4));
}
__device__ __forceinline__ int h2_addr(int m, int kb) {
    return H2_OFF + ((m * 512 + kb) ^ ((m & 7) << 4));
}

// ---- prep: pack U,W (fp32) into bf16 MFMA B-fragment order in d_ws ----
// B-frag for 16x16x32: lane l holds B[k = kt*32 + (l>>4)*8 + j][n = nt*16 + (l&15)]
// Upk frag slot = kt*16+nt (kt<32, nt<16); Wpk frag slot = kt*64+nt (kt<8, nt<64)
__global__ __launch_bounds__(256)
void prep_pack(const float* __restrict__ U, const float* __restrict__ Wm,
               bf16x8* __restrict__ pk)
{
    const int tid  = blockIdx.x * 256 + threadIdx.x;   // 0..65535
    const int lane = tid & 63;
    const int frag = tid >> 6;                          // 0..1023
    bf16x8 o;
    if (frag < 512) {
        const int kt = frag >> 4, nt = frag & 15;
        const int krow = kt * 32 + (lane >> 4) * 8;
        const int n    = nt * 16 + (lane & 15);
        #pragma unroll
        for (int j = 0; j < 8; ++j) o[j] = (short)f2bf(U[(krow + j) * RANK + n]);
    } else {
        const int f = frag - 512;
        const int kt = f >> 6, nt = f & 63;
        const int krow = kt * 32 + (lane >> 4) * 8;
        const int n    = nt * 16 + (lane & 15);
        #pragma unroll
        for (int j = 0; j < 8; ++j) o[j] = (short)f2bf(Wm[(krow + j) * DIM + n]);
    }
    pk[frag * 64 + lane] = o;   // frag>=512 lands exactly at Wpk base (32768)
}

__global__ __launch_bounds__(NTHREADS, 1)
void omelyan_mfma(const float* __restrict__ x_in,
                  const float* __restrict__ v_in,
                  const float* __restrict__ force,
                  const float* __restrict__ Vw,
                  const int* __restrict__ steps_p,
                  const bf16x8* __restrict__ pk,
                  float* __restrict__ out)
{
    extern __shared__ char smem[];
    float* gs    = (float*)(smem + GS_OFF);
    float* wsums = (float*)(smem + WS_OFF);
    float* sings = (float*)(smem + SG_OFF);

    const int t    = threadIdx.x;
    const int lane = t & 63;
    const int w    = t >> 6;
    const int row0 = blockIdx.x * NROWS;
    const int nsteps = steps_p[0];

    const float dt = 0.01f;

    // per-thread state: element (m, d = 4t+j)
    float xr[NROWS][4], vr[NROWS][4];
    const f32x4 vw = *(const f32x4*)&Vw[4 * t];

    #pragma unroll
    for (int m = 0; m < NROWS; ++m) {
        const int base = (row0 + m) * DIM + 4 * t;
        const f32x4 xv = *(const f32x4*)&x_in[base];
        const f32x4 vv = *(const f32x4*)&v_in[base];
        us4 p;
        #pragma unroll
        for (int j = 0; j < 4; ++j) {
            xr[m][j] = xv[j]; vr[m][j] = vv[j];
            p[j] = f2bf(vv[j]);
        }
        *(us4*)(smem + vs_addr(m, 8 * t)) = p;
    }
    __syncthreads();

    #pragma unroll 1
    for (int step = 0; step < nsteps; ++step) {
        #pragma unroll 1
        for (int sub = 0; sub < 4; ++sub) {
            const float cdt = dt * (sub == 0 ? (float)XI :
                                    sub == 1 ? (float)CHI :
                                    sub == 2 ? (float)(1.0 - 2.0 * (CHI + XI)) :
                                               (float)CHI);
            const float ddt = dt * ((sub == 0 || sub == 3)
                                    ? (float)((1.0 - 2.0 * LAM) * 0.5)
                                    : (float)LAM);

            // ---- drift x, r2 reduce ----
            #pragma unroll
            for (int m = 0; m < NROWS; ++m) {
                float s = 0.f;
                #pragma unroll
                for (int j = 0; j < 4; ++j) {
                    xr[m][j] = fmaf(cdt, vr[m][j], xr[m][j]);
                    s = fmaf(xr[m][j], xr[m][j], s);
                }
                #pragma unroll
                for (int off = 32; off >= 1; off >>= 1) s += __shfl_xor(s, off, 64);
                if (lane == 0) wsums[m * 4 + w] = s;
            }
            __syncthreads();                            // b1
            if (t < NROWS) {
                const float r2 = wsums[t*4] + wsums[t*4+1] + wsums[t*4+2] + wsums[t*4+3];
                sings[t] = 1.f + exp2f(-r2 * 1.4426950408889634f);
            }

            // ---- H: h = v @ U  (M=16, N=256, K=1024), wave owns 4 n-tiles ----
            {
                const int nt0 = w * 4;
                f32x4 hacc[4];
                #pragma unroll
                for (int i = 0; i < 4; ++i) hacc[i] = (f32x4){0.f, 0.f, 0.f, 0.f};
                bf16x8 bb[2][4];
                #pragma unroll
                for (int i = 0; i < 4; ++i) bb[0][i] = pk[(0 * 16 + nt0 + i) * 64 + lane];
                #pragma unroll
                for (int i = 0; i < 4; ++i) bb[1][i] = pk[(1 * 16 + nt0 + i) * 64 + lane];
                bf16x8 a0 = *(const bf16x8*)(smem + vs_addr(lane & 15, (lane >> 4) * 16));
                #pragma unroll
                for (int k = 0; k < 32; ++k) {
                    const int kn = (k + 1 < 32) ? k + 1 : 0;
                    bf16x8 a1 = *(const bf16x8*)(smem + vs_addr(lane & 15, kn * 64 + (lane >> 4) * 16));
                    #pragma unroll
                    for (int i = 0; i < 4; ++i)
                        hacc[i] = __builtin_amdgcn_mfma_f32_16x16x32_bf16(a0, bb[k & 1][i], hacc[i], 0, 0, 0);
                    if (k + 2 < 32) {
                        #pragma unroll
                        for (int i = 0; i < 4; ++i)
                            bb[k & 1][i] = pk[((k + 2) * 16 + nt0 + i) * 64 + lane];
                    }
                    a0 = a1;
                }
                // h2 = (h*h) in bf16, swizzled; D-layout: col=lane&15, row=(lane>>4)*4+r
                #pragma unroll
                for (int i = 0; i < 4; ++i) {
                    #pragma unroll
                    for (int r = 0; r < 4; ++r) {
                        const int m = (lane >> 4) * 4 + r;
                        const int n = (nt0 + i) * 16 + (lane & 15);
                        const float h = hacc[i][r];
                        *(unsigned short*)(smem + h2_addr(m, 2 * n)) = f2bf(h * h);
                    }
                }
            }
            __syncthreads();                            // b2

            // ---- G: gamma = h2 @ W (M=16, N=1024, K=256), 4 passes x 4 n-tiles ----
            #pragma unroll 1
            for (int p = 0; p < 4; ++p) {
                const int nt0g = w * 16 + p * 4;
                f32x4 gacc[4];
                #pragma unroll
                for (int i = 0; i < 4; ++i) gacc[i] = (f32x4){0.f, 0.f, 0.f, 0.f};
                bf16x8 wb[2][4];
                #pragma unroll
                for (int i = 0; i < 4; ++i) wb[0][i] = pk[32768 + (0 * 64 + nt0g + i) * 64 + lane];
                #pragma unroll
                for (int i = 0; i < 4; ++i) wb[1][i] = pk[32768 + (1 * 64 + nt0g + i) * 64 + lane];
                bf16x8 a0 = *(const bf16x8*)(smem + h2_addr(lane & 15, (lane >> 4) * 16));
                #pragma unroll
                for (int k = 0; k < 8; ++k) {
                    const int kn = (k + 1 < 8) ? k + 1 : 0;
                    bf16x8 a1 = *(const bf16x8*)(smem + h2_addr(lane & 15, kn * 64 + (lane >> 4) * 16));
                    #pragma unroll
                    for (int i = 0; i < 4; ++i)
                        gacc[i] = __builtin_amdgcn_mfma_f32_16x16x32_bf16(a0, wb[k & 1][i], gacc[i], 0, 0, 0);
                    if (k + 2 < 8) {
                        #pragma unroll
                        for (int i = 0; i < 4; ++i)
                            wb[k & 1][i] = pk[32768 + ((k + 2) * 64 + nt0g + i) * 64 + lane];
                    }
                    a0 = a1;
                }
                #pragma unroll
                for (int i = 0; i < 4; ++i) {
                    #pragma unroll
                    for (int r = 0; r < 4; ++r)
                        gs[((lane >> 4) * 4 + r) * GS_PITCH + (nt0g + i) * 16 + (lane & 15)] = gacc[i][r];
                }
            }
            __syncthreads();                            // b3

            // ---- kick: v += ddt * (force - gamma*gate*sing); refresh vs ----
            #pragma unroll
            for (int m = 0; m < NROWS; ++m) {
                const f32x4 g4 = *(const f32x4*)&gs[m * GS_PITCH + 4 * t];
                const f32x4 f4 = *(const f32x4*)&force[(row0 + m) * DIM + 4 * t];
                const float sing = sings[m];
                us4 pkk;
                #pragma unroll
                for (int j = 0; j < 4; ++j) {
                    const float z  = xr[m][j] * vw[j];
                    const float e  = exp2f(z * 2.885390081777927f);   // e^(2z)
                    const float th = 1.f - 2.f / (e + 1.f);           // tanh(z)
                    const float gate = fmaf(0.1f, th, 1.f);
                    const float a = f4[j] - g4[j] * gate * sing;
                    vr[m][j] = fmaf(ddt, a, vr[m][j]);
                    pkk[j] = f2bf(vr[m][j]);
                }
                *(us4*)(smem + vs_addr(m, 8 * t)) = pkk;
            }
        } // sub

        // final drift: x += C5*dt*v
        const float c5dt = dt * (float)XI;
        #pragma unroll
        for (int m = 0; m < NROWS; ++m)
            #pragma unroll
            for (int j = 0; j < 4; ++j)
                xr[m][j] = fmaf(c5dt, vr[m][j], xr[m][j]);
    } // step

    // ---- store (x, v) ----
    #pragma unroll
    for (int m = 0; m < NROWS; ++m) {
        const int base = (row0 + m) * DIM + 4 * t;
        f32x4 xo, vo;
        #pragma unroll
        for (int j = 0; j < 4; ++j) { xo[j] = xr[m][j]; vo[j] = vr[m][j]; }
        *(f32x4*)&out[base] = xo;
        *(f32x4*)&out[OUT_HALF + base] = vo;
    }
}

extern "C" void kernel_launch(void* const* d_in, const int* in_sizes, int n_in,
                              void* d_out, int out_size, void* d_ws, size_t ws_size,
                              hipStream_t stream) {
    const float* x_in  = (const float*)d_in[0];
    const float* v_in  = (const float*)d_in[1];
    const float* force = (const float*)d_in[2];
    const float* Umat  = (const float*)d_in[3];
    const float* Wmat  = (const float*)d_in[4];
    const float* Vw    = (const float*)d_in[5];
    const int*   steps = (const int*)d_in[6];
    float* out = (float*)d_out;
    bf16x8* pk = (bf16x8*)d_ws;   // needs 1 MiB

    (void)hipFuncSetAttribute((const void*)omelyan_mfma,
                              hipFuncAttributeMaxDynamicSharedMemorySize,
                              SMEM_BYTES);

    prep_pack<<<dim3(256), dim3(256), 0, stream>>>(Umat, Wmat, pk);
    omelyan_mfma<<<dim3(TOTAL_ROWS / NROWS), dim3(NTHREADS), SMEM_BYTES, stream>>>(
        x_in, v_in, force, Vw, steps, pk, out);
}

// Round 3
// 612.373 us; speedup vs baseline: 3.1117x; 1.4201x over previous
//
#include <hip/hip_runtime.h>
#include <math.h>

typedef short  bf16x8 __attribute__((ext_vector_type(8)));
typedef float  f32x4  __attribute__((ext_vector_type(4)));
typedef float  f32x2  __attribute__((ext_vector_type(2)));

#define DIM   1024
#define RANK  256
#define NROWS 16
#define NT    512
#define NWAVE 8
#define TOTAL_ROWS 4096
#define OUT_HALF (TOTAL_ROWS*DIM)

// LDS byte layout
#define VS_OFF   0            // ushort[16][1024], XOR-swizzled rows (32768 B)
#define H2_OFF   32768        // ushort[16][256],  XOR-swizzled rows (8192 B)
#define GS_OFF   40960        // float [16][1028] pitch-padded (65792 B)
#define GS_PITCH 1028
#define WS_OFF   106752       // float [16][8]
#define SG_OFF   107264       // float [16]
#define SMEM_BYTES 107328

static constexpr double XI  = 0.1786178958448091;
static constexpr double LAM = -0.2123418310626054;
static constexpr double CHI = -0.0662645826698185;

__device__ __forceinline__ unsigned short f2bf(float f) {
    unsigned u = __builtin_bit_cast(unsigned, f);
    u += 0x7FFFu + ((u >> 16) & 1u);        // round-to-nearest-even
    return (unsigned short)(u >> 16);
}

// swizzle: byte ^= (row&7)<<4 -> 16 A-rows spread over 8 16B slots
__device__ __forceinline__ int vs_addr(int m, int kb) {
    return VS_OFF + ((m * 2048 + kb) ^ ((m & 7) << 4));
}
__device__ __forceinline__ int h2_addr(int m, int kb) {
    return H2_OFF + ((m * 512 + kb) ^ ((m & 7) << 4));
}

// ---- prep: pack U,W (fp32) into bf16 MFMA B-fragment order in d_ws ----
// B-frag 16x16x32: lane l holds B[k = kt*32 + (l>>4)*8 + j][n = nt*16 + (l&15)]
// U slot = kt*16+nt (kt<32,nt<16); W slot = 512 + kt*64+nt (kt<8,nt<64)
__global__ __launch_bounds__(256)
void prep_pack(const float* __restrict__ U, const float* __restrict__ Wm,
               bf16x8* __restrict__ pk)
{
    const int tid  = blockIdx.x * 256 + threadIdx.x;   // 0..65535
    const int lane = tid & 63;
    const int frag = tid >> 6;                          // 0..1023
    bf16x8 o;
    if (frag < 512) {
        const int kt = frag >> 4, nt = frag & 15;
        const int krow = kt * 32 + (lane >> 4) * 8;
        const int n    = nt * 16 + (lane & 15);
        #pragma unroll
        for (int j = 0; j < 8; ++j) o[j] = (short)f2bf(U[(krow + j) * RANK + n]);
    } else {
        const int f = frag - 512;
        const int kt = f >> 6, nt = f & 63;
        const int krow = kt * 32 + (lane >> 4) * 8;
        const int n    = nt * 16 + (lane & 15);
        #pragma unroll
        for (int j = 0; j < 8; ++j) o[j] = (short)f2bf(Wm[(krow + j) * DIM + n]);
    }
    pk[frag * 64 + lane] = o;
}

__global__ __launch_bounds__(NT, 2)
void omelyan_mfma(const float* __restrict__ x_in,
                  const float* __restrict__ v_in,
                  const float* __restrict__ force,
                  const float* __restrict__ Vw,
                  const int* __restrict__ steps_p,
                  const bf16x8* __restrict__ pk,
                  float* __restrict__ out)
{
    extern __shared__ char smem[];
    float* gs    = (float*)(smem + GS_OFF);
    float* wsums = (float*)(smem + WS_OFF);
    float* sings = (float*)(smem + SG_OFF);

    const int t    = threadIdx.x;        // 0..511
    const int lane = t & 63;
    const int w    = t >> 6;             // 0..7
    const int row0 = blockIdx.x * NROWS;
    const int nsteps = steps_p[0];

    const float dt = 0.01f;

    // per-thread elementwise state: element (m, d = 2t+j), j=0,1
    float xr[NROWS][2], vr[NROWS][2], fr[NROWS][2];
    f32x2 vw = *(const f32x2*)&Vw[2 * t];

    #pragma unroll
    for (int m = 0; m < NROWS; ++m) {
        const int base = (row0 + m) * DIM + 2 * t;
        const f32x2 xv = *(const f32x2*)&x_in[base];
        const f32x2 vv = *(const f32x2*)&v_in[base];
        const f32x2 fv = *(const f32x2*)&force[base];
        xr[m][0] = xv[0]; xr[m][1] = xv[1];
        vr[m][0] = vv[0]; vr[m][1] = vv[1];
        fr[m][0] = fv[0]; fr[m][1] = fv[1];
        const unsigned p = (unsigned)f2bf(vv[0]) | ((unsigned)f2bf(vv[1]) << 16);
        *(unsigned*)(smem + vs_addr(m, 4 * t)) = p;
    }
    __syncthreads();

    #pragma unroll 1
    for (int step = 0; step < nsteps; ++step) {
        #pragma unroll 1
        for (int sub = 0; sub < 4; ++sub) {
            const float cdt = dt * (sub == 0 ? (float)XI :
                                    sub == 1 ? (float)CHI :
                                    sub == 2 ? (float)(1.0 - 2.0 * (CHI + XI)) :
                                               (float)CHI);
            const float ddt = dt * ((sub == 0 || sub == 3)
                                    ? (float)((1.0 - 2.0 * LAM) * 0.5)
                                    : (float)LAM);

            // ---- drift x, r2 reduce ----
            #pragma unroll
            for (int m = 0; m < NROWS; ++m) {
                float s = 0.f;
                #pragma unroll
                for (int j = 0; j < 2; ++j) {
                    xr[m][j] = fmaf(cdt, vr[m][j], xr[m][j]);
                    s = fmaf(xr[m][j], xr[m][j], s);
                }
                #pragma unroll
                for (int off = 32; off >= 1; off >>= 1) s += __shfl_xor(s, off, 64);
                if (lane == 0) wsums[m * NWAVE + w] = s;
            }
            __syncthreads();                            // b1
            if (t < NROWS) {
                float r2 = 0.f;
                #pragma unroll
                for (int q = 0; q < NWAVE; ++q) r2 += wsums[t * NWAVE + q];
                sings[t] = 1.f + exp2f(-r2 * 1.4426950408889634f);
            }

            // ---- H: h = v @ U (M=16,N=256,K=1024); wave owns 2 n-tiles ----
            {
                const int nt0 = w * 2;
                f32x4 hacc[2];
                #pragma unroll
                for (int i = 0; i < 2; ++i) hacc[i] = (f32x4){0.f, 0.f, 0.f, 0.f};
                bf16x8 bb[8][2];                        // ring-8 prefetch
                #pragma unroll
                for (int s = 0; s < 8; ++s)
                    #pragma unroll
                    for (int i = 0; i < 2; ++i)
                        bb[s][i] = pk[(s * 16 + nt0 + i) * 64 + lane];
                bf16x8 a0 = *(const bf16x8*)(smem + vs_addr(lane & 15, (lane >> 4) * 16));
                #pragma unroll
                for (int k = 0; k < 32; ++k) {
                    const int kn = (k + 1) & 31;
                    bf16x8 a1 = *(const bf16x8*)(smem + vs_addr(lane & 15, kn * 64 + (lane >> 4) * 16));
                    #pragma unroll
                    for (int i = 0; i < 2; ++i)
                        hacc[i] = __builtin_amdgcn_mfma_f32_16x16x32_bf16(a0, bb[k & 7][i], hacc[i], 0, 0, 0);
                    if (k + 8 < 32) {
                        #pragma unroll
                        for (int i = 0; i < 2; ++i)
                            bb[k & 7][i] = pk[((k + 8) * 16 + nt0 + i) * 64 + lane];
                    }
                    a0 = a1;
                }
                // h2 = (h*h) bf16, swizzled; D: col=lane&15, row=(lane>>4)*4+r
                #pragma unroll
                for (int i = 0; i < 2; ++i) {
                    #pragma unroll
                    for (int r = 0; r < 4; ++r) {
                        const int m = (lane >> 4) * 4 + r;
                        const int n = (nt0 + i) * 16 + (lane & 15);
                        const float h = hacc[i][r];
                        *(unsigned short*)(smem + h2_addr(m, 2 * n)) = f2bf(h * h);
                    }
                }
            }
            __syncthreads();                            // b2

            // ---- G: gamma = h2 @ W (M=16,N=1024,K=256); 2 passes x 4 n-tiles ----
            #pragma unroll 1
            for (int p = 0; p < 2; ++p) {
                const int ntg = w * 8 + p * 4;
                f32x4 gacc[4];
                #pragma unroll
                for (int i = 0; i < 4; ++i) gacc[i] = (f32x4){0.f, 0.f, 0.f, 0.f};
                bf16x8 wb[4][4];                        // ring-4 prefetch
                #pragma unroll
                for (int s = 0; s < 4; ++s)
                    #pragma unroll
                    for (int i = 0; i < 4; ++i)
                        wb[s][i] = pk[32768 + (s * 64 + ntg + i) * 64 + lane];
                bf16x8 a0 = *(const bf16x8*)(smem + h2_addr(lane & 15, (lane >> 4) * 16));
                #pragma unroll
                for (int k = 0; k < 8; ++k) {
                    const int kn = (k + 1) & 7;
                    bf16x8 a1 = *(const bf16x8*)(smem + h2_addr(lane & 15, kn * 64 + (lane >> 4) * 16));
                    #pragma unroll
                    for (int i = 0; i < 4; ++i)
                        gacc[i] = __builtin_amdgcn_mfma_f32_16x16x32_bf16(a0, wb[k & 3][i], gacc[i], 0, 0, 0);
                    if (k + 4 < 8) {
                        #pragma unroll
                        for (int i = 0; i < 4; ++i)
                            wb[k & 3][i] = pk[32768 + ((k + 4) * 64 + ntg + i) * 64 + lane];
                    }
                    a0 = a1;
                }
                #pragma unroll
                for (int i = 0; i < 4; ++i)
                    #pragma unroll
                    for (int r = 0; r < 4; ++r)
                        gs[((lane >> 4) * 4 + r) * GS_PITCH + (ntg + i) * 16 + (lane & 15)] = gacc[i][r];
            }
            __syncthreads();                            // b3

            // ---- kick: v += ddt*(force - gamma*gate*sing); refresh vs ----
            #pragma unroll
            for (int m = 0; m < NROWS; ++m) {
                const f32x2 g2 = *(const f32x2*)&gs[m * GS_PITCH + 2 * t];
                const float sing = sings[m];
                unsigned pp = 0;
                #pragma unroll
                for (int j = 0; j < 2; ++j) {
                    const float z  = xr[m][j] * vw[j];
                    const float e  = exp2f(z * 2.885390081777927f);   // e^(2z)
                    const float th = 1.f - 2.f / (e + 1.f);           // tanh(z)
                    const float gate = fmaf(0.1f, th, 1.f);
                    const float a = fr[m][j] - g2[j] * gate * sing;
                    vr[m][j] = fmaf(ddt, a, vr[m][j]);
                    pp |= ((unsigned)f2bf(vr[m][j])) << (16 * j);
                }
                *(unsigned*)(smem + vs_addr(m, 4 * t)) = pp;
            }
            __syncthreads();                            // b4
        } // sub

        // final drift: x += C5*dt*v
        const float c5dt = dt * (float)XI;
        #pragma unroll
        for (int m = 0; m < NROWS; ++m)
            #pragma unroll
            for (int j = 0; j < 2; ++j)
                xr[m][j] = fmaf(c5dt, vr[m][j], xr[m][j]);
    } // step

    // ---- store (x, v) ----
    #pragma unroll
    for (int m = 0; m < NROWS; ++m) {
        const int base = (row0 + m) * DIM + 2 * t;
        f32x2 xo, vo;
        xo[0] = xr[m][0]; xo[1] = xr[m][1];
        vo[0] = vr[m][0]; vo[1] = vr[m][1];
        *(f32x2*)&out[base] = xo;
        *(f32x2*)&out[OUT_HALF + base] = vo;
    }
}

extern "C" void kernel_launch(void* const* d_in, const int* in_sizes, int n_in,
                              void* d_out, int out_size, void* d_ws, size_t ws_size,
                              hipStream_t stream) {
    const float* x_in  = (const float*)d_in[0];
    const float* v_in  = (const float*)d_in[1];
    const float* force = (const float*)d_in[2];
    const float* Umat  = (const float*)d_in[3];
    const float* Wmat  = (const float*)d_in[4];
    const float* Vw    = (const float*)d_in[5];
    const int*   steps = (const int*)d_in[6];
    float* out = (float*)d_out;
    bf16x8* pk = (bf16x8*)d_ws;   // 1 MiB

    (void)hipFuncSetAttribute((const void*)omelyan_mfma,
                              hipFuncAttributeMaxDynamicSharedMemorySize,
                              SMEM_BYTES);

    prep_pack<<<dim3(256), dim3(256), 0, stream>>>(Umat, Wmat, pk);
    omelyan_mfma<<<dim3(TOTAL_ROWS / NROWS), dim3(NT), SMEM_BYTES, stream>>>(
        x_in, v_in, force, Vw, steps, pk, out);
}